// Round 3
// baseline (349.135 us; speedup 1.0000x reference)
//
#include <hip/hip_runtime.h>
#include <hip/hip_bf16.h>

typedef __attribute__((ext_vector_type(8))) short bf16x8;
typedef __attribute__((ext_vector_type(4))) float f32x4;
typedef __attribute__((ext_vector_type(8))) unsigned short u16x8;

#define B_DIM 8192
#define H_DIM 1024
#define K_DIM 2048
#define N_DIM 4096
#define BH (B_DIM * H_DIM)

__device__ __forceinline__ unsigned short f2bf(float f) {
    union { float f; unsigned u; } v; v.f = f;
    unsigned r = v.u + 0x7FFFu + ((v.u >> 16) & 1u);   // round-to-nearest-even
    return (unsigned short)(r >> 16);
}

__device__ __forceinline__ void gload16(const void* g, void* l) {
    __builtin_amdgcn_global_load_lds(
        (const __attribute__((address_space(1))) void*)g,
        (__attribute__((address_space(3))) void*)l, 16, 0, 0);
}

// ---------------------------------------------------------------------------
// prep_a: pack [x|h] fp32 -> bf16 A[8192][2048], 32B out per thread
// ---------------------------------------------------------------------------
__global__ void prep_a(const float* __restrict__ x, const float* __restrict__ h,
                       unsigned short* __restrict__ Abf) {
    int gid = blockIdx.x * 256 + threadIdx.x;       // 16 elems per thread
    size_t e = (size_t)gid * 16;
    int m   = gid >> 7;                             // 128 threads per 2048-row
    int col = (gid & 127) * 16;                     // never straddles the 1024 split
    const float* src = (col >= 1024) ? (h + (size_t)m * 1024 + col - 1024)
                                     : (x + (size_t)m * 1024 + col);
    float4 v0 = *(const float4*)(src + 0);
    float4 v1 = *(const float4*)(src + 4);
    float4 v2 = *(const float4*)(src + 8);
    float4 v3 = *(const float4*)(src + 12);
    u16x8 o0 = { f2bf(v0.x), f2bf(v0.y), f2bf(v0.z), f2bf(v0.w),
                 f2bf(v1.x), f2bf(v1.y), f2bf(v1.z), f2bf(v1.w) };
    u16x8 o1 = { f2bf(v2.x), f2bf(v2.y), f2bf(v2.z), f2bf(v2.w),
                 f2bf(v3.x), f2bf(v3.y), f2bf(v3.z), f2bf(v3.w) };
    *(u16x8*)(Abf + e)     = o0;
    *(u16x8*)(Abf + e + 8) = o1;
}

// ---------------------------------------------------------------------------
// prep_b: W=[Wx;Wh] fp32 [2048][4096] -> Bpack, FRAGMENT-PACKED bf16.
// Logical B^T row n = gate*1024 + j, col k. Fragment coords:
//   jb=j>>5, wn=(j>>4)&1, fR=j&15 ; kt=k>>6, ks=(k>>5)&1, qB=(k>>3)&3, e=k&7
// off = jb*262144 + wn*131072 + kt*4096 + ks*2048 + gate*512 + (qB*16+fR)*8 + e
// so one (jb,wn,kt,ks,gate) fragment = contiguous 1KB, lane-ordered.
// ---------------------------------------------------------------------------
__global__ void prep_b(const float* __restrict__ Wx, const float* __restrict__ Wh,
                       unsigned short* __restrict__ Bpack) {
    __shared__ float tile[64][65];
    const int t  = threadIdx.x;
    const int k0 = (blockIdx.x & 31) * 64;
    const int n0 = (blockIdx.x >> 5) * 64;
#pragma unroll
    for (int it = 0; it < 4; ++it) {
        int lin = it * 256 + t;
        int kl  = lin >> 4;
        int n4  = lin & 15;
        int k   = k0 + kl;
        const float* src = (k < 1024) ? (Wx + (size_t)k * 4096 + n0 + n4 * 4)
                                      : (Wh + (size_t)(k - 1024) * 4096 + n0 + n4 * 4);
        float4 v = *(const float4*)src;
        tile[kl][n4 * 4 + 0] = v.x;
        tile[kl][n4 * 4 + 1] = v.y;
        tile[kl][n4 * 4 + 2] = v.z;
        tile[kl][n4 * 4 + 3] = v.w;
    }
    __syncthreads();
#pragma unroll
    for (int it = 0; it < 2; ++it) {
        int lin = it * 256 + t;
        int nl  = lin >> 3;
        int ch  = lin & 7;                          // k-chunk of 8 within 64
        int n    = n0 + nl;
        int gate = n >> 10;
        int j    = n & 1023;
        int jb   = j >> 5;
        int wn   = (j >> 4) & 1;
        int fR   = j & 15;
        int kt   = k0 >> 6;
        int ks   = ch >> 2;
        int qB   = ch & 3;
        size_t off = (size_t)jb * 262144 + wn * 131072 + kt * 4096 + ks * 2048
                   + gate * 512 + (qB * 16 + fR) * 8;
        u16x8 o;
#pragma unroll
        for (int q = 0; q < 8; ++q) o[q] = f2bf(tile[ch * 8 + q][nl]);
        *(u16x8*)(Bpack + off) = o;
    }
}

// ---------------------------------------------------------------------------
// fused GEMM + LSTM epilogue. 128x128 tile, BK=64, 4 waves, 16x16x32 bf16.
// A: LDS-staged via global_load_lds (XOR-swizzled). B: direct-to-VGPR from
// fragment-packed Bpack, double-buffered across kt (prefetch before barrier).
// ---------------------------------------------------------------------------
__global__ __launch_bounds__(256, 3) void lstm_fused(
    const unsigned short* __restrict__ Abf,   // [8192][2048] bf16
    const unsigned short* __restrict__ Bpack, // fragment-packed bf16
    const float* __restrict__ bx, const float* __restrict__ bh,
    const float* __restrict__ cin, float* __restrict__ out) {
    __shared__ unsigned short lsA[128 * 64];

    const int tid  = threadIdx.x;
    const int wave = tid >> 6;
    const int lane = tid & 63;
    const int m0 = blockIdx.x * 128;
    const int jb = blockIdx.y;                  // 0..31
    const int wm = wave >> 1;
    const int wn = wave & 1;

    f32x4 acc[4][4];
#pragma unroll
    for (int i = 0; i < 4; ++i)
#pragma unroll
        for (int j = 0; j < 4; ++j) acc[i][j] = (f32x4){0.f, 0.f, 0.f, 0.f};

    const int sRow   = tid >> 3;
    const int sChunk = (((tid & 7) ^ ((tid >> 3) & 7))) * 8;  // XOR swizzle
    const int aBase  = (m0 + sRow) * K_DIM + sChunk;

    const int fRow  = lane & 15;
    const int qBase = lane >> 4;                // 0..3
    const int rx    = fRow & 7;

    const unsigned short* bPtr = Bpack + (size_t)jb * 262144 + wn * 131072 + lane * 8;

    bf16x8 bbuf[2][8];
#pragma unroll
    for (int ks = 0; ks < 2; ++ks)
#pragma unroll
        for (int tn = 0; tn < 4; ++tn)
            bbuf[0][ks * 4 + tn] = *(const bf16x8*)(bPtr + ks * 2048 + tn * 512);

#pragma unroll 2
    for (int kt = 0; kt < 32; ++kt) {
        const int p = kt & 1;
        const int kOff = kt * 64;
#pragma unroll
        for (int it = 0; it < 4; ++it)
            gload16(Abf + aBase + it * (32 * K_DIM) + kOff, lsA + it * 2048 + wave * 512);
        const int ktn = (kt == 31) ? 31 : kt + 1;   // clamped prefetch
#pragma unroll
        for (int ks = 0; ks < 2; ++ks)
#pragma unroll
            for (int tn = 0; tn < 4; ++tn)
                bbuf[p ^ 1][ks * 4 + tn] =
                    *(const bf16x8*)(bPtr + ktn * 4096 + ks * 2048 + tn * 512);
        __syncthreads();                            // drains A-stage + B-prefetch
#pragma unroll
        for (int ks = 0; ks < 2; ++ks) {
            bf16x8 af[4];
            const int qPhys = (ks * 4 + qBase) ^ rx;
#pragma unroll
            for (int tm = 0; tm < 4; ++tm)
                af[tm] = *(const bf16x8*)(lsA + (wm * 64 + tm * 16 + fRow) * 64 + qPhys * 8);
#pragma unroll
            for (int tm = 0; tm < 4; ++tm)
#pragma unroll
                for (int tn = 0; tn < 4; ++tn)
                    acc[tm][tn] = __builtin_amdgcn_mfma_f32_16x16x32_bf16(
                        af[tm], bbuf[p][ks * 4 + tn], acc[tm][tn], 0, 0, 0);
        }
        __syncthreads();                            // lsA reuse protection
    }

    // Epilogue: tn indexes gate {i,f,g,o}; j fixed per lane.
    const int j = jb * 32 + wn * 16 + fRow;
    const float b_i = bx[j] + bh[j];
    const float b_f = bx[1024 + j] + bh[1024 + j];
    const float b_g = bx[2048 + j] + bh[2048 + j];
    const float b_o = bx[3072 + j] + bh[3072 + j];
#pragma unroll
    for (int tm = 0; tm < 4; ++tm) {
#pragma unroll
        for (int r = 0; r < 4; ++r) {
            const int row = m0 + wm * 64 + tm * 16 + qBase * 4 + r;
            float vi = acc[tm][0][r] + b_i;
            float vf = acc[tm][1][r] + b_f;
            float vg = acc[tm][2][r] + b_g;
            float vo = acc[tm][3][r] + b_o;
            float ig = 1.f / (1.f + __expf(-vi));
            float fg = 1.f / (1.f + __expf(-vf));
            float e2g = __expf(2.f * fminf(fmaxf(vg, -15.f), 15.f));
            float gg = (e2g - 1.f) / (e2g + 1.f);
            float og = 1.f / (1.f + __expf(-vo));
            float cn = fg * cin[(size_t)row * 1024 + j] + ig * gg;
            float e2c = __expf(2.f * fminf(fmaxf(cn, -15.f), 15.f));
            float hn = og * ((e2c - 1.f) / (e2c + 1.f));
            out[(size_t)row * 1024 + j] = og;
            out[(size_t)BH + (size_t)row * 1024 + j] = hn;
            out[(size_t)2 * BH + (size_t)row * 1024 + j] = cn;
        }
    }
}

extern "C" void kernel_launch(void* const* d_in, const int* in_sizes, int n_in,
                              void* d_out, int out_size, void* d_ws, size_t ws_size,
                              hipStream_t stream) {
    const float* x  = (const float*)d_in[0];
    const float* h  = (const float*)d_in[1];
    const float* c  = (const float*)d_in[2];
    const float* Wx = (const float*)d_in[3];
    const float* Wh = (const float*)d_in[4];
    const float* bx = (const float*)d_in[5];
    const float* bh = (const float*)d_in[6];
    float* out = (float*)d_out;

    unsigned short* Abf   = (unsigned short*)d_ws;                                      // 32 MB
    unsigned short* Bpack = (unsigned short*)((char*)d_ws + (size_t)B_DIM * K_DIM * 2); // 16 MB

    hipLaunchKernelGGL(prep_b, dim3(2048), dim3(256), 0, stream, Wx, Wh, Bpack);
    hipLaunchKernelGGL(prep_a, dim3(4096), dim3(256), 0, stream, x, h, Abf);
    hipLaunchKernelGGL(lstm_fused, dim3(B_DIM / 128, 32), dim3(256), 0, stream,
                       Abf, Bpack, bx, bh, c, out);
}